// Round 3
// baseline (62464.630 us; speedup 1.0000x reference)
//
#include <hip/hip_runtime.h>
#include <hip/hip_bf16.h>
#include <stdint.h>

#define NS 4096     // samples / time steps
#define DT 1024     // dim_t == hidden == in
#define H4 4096     // 4*HID

// ---------- math helpers ----------
__device__ __forceinline__ float sigm_f(float x) { return 1.f / (1.f + __expf(-x)); }
__device__ __forceinline__ float tanh_f(float x) {
    float ax = fminf(fabsf(x), 15.f);                 // overflow-safe
    float t = 1.f - 2.f / (__expf(2.f * ax) + 1.f);
    return copysignf(t, x);
}

// ---------- sinusoidal embedding ----------
__global__ void emb_kernel(const int* __restrict__ ts, float* __restrict__ emb) {
    int t = blockIdx.x;
    int i = threadIdx.x;                 // 0..511
    float tv = (float)ts[t];
    const float c = -0.018024149455922082f;  // -ln(10000)/511
    float f = __expf(c * (float)i);
    float a = tv * f;
    float s, co;
    sincosf(a, &s, &co);
    emb[(size_t)t * DT + i] = s;
    emb[(size_t)t * DT + 512 + i] = co;
}

// ---------- generic C = A(M,K) @ B(Nc,K)^T + bias [+bias2] [+skip] [silu] ----------
// BM=128, BN=64, BK=16, 256 threads, each thread 8x4 outputs.
// XGMODE: 0 = plain fp32 C; 1 = bf16 XG layout; 2 = fp32 XG layout.
// XG layout per epoch (4096 elems): pos = k*16 + r*4 + q for col = q*1024 + 4k + r.
template <bool SILU, bool SKIP, int XGMODE>
__global__ __launch_bounds__(256) void gemm_bt(
    const float* __restrict__ A, const float* __restrict__ B,
    const float* __restrict__ bias, const float* __restrict__ bias2,
    const float* __restrict__ skip, float* __restrict__ Cf,
    __hip_bfloat16* __restrict__ Cb, int M, int Nc, int K)
{
    __shared__ __align__(16) float As[16][132];
    __shared__ __align__(16) float Bs[16][68];
    const int bn = blockIdx.x, bm = blockIdx.y, lz = blockIdx.z;
    if (XGMODE) {
        B     += (size_t)lz * H4 * DT;
        bias  += (size_t)lz * H4;
        bias2 += (size_t)lz * H4;
    }
    const int tid = threadIdx.x;
    const int tr = tid >> 4, tc = tid & 15;
    const int alr = tid >> 1, alc = (tid & 1) << 3;   // A: 128 rows x 16 cols
    const int blr = tid >> 2, blc = (tid & 3) << 2;   // B: 64 rows x 16 cols
    const float* Ap = A + (size_t)(bm * 128 + alr) * K + alc;
    const float* Bp = B + (size_t)(bn * 64 + blr) * K + blc;

    float acc[8][4];
#pragma unroll
    for (int i = 0; i < 8; i++)
#pragma unroll
        for (int j = 0; j < 4; j++) acc[i][j] = 0.f;

    for (int kk = 0; kk < K; kk += 16) {
        float4 a0 = *(const float4*)(Ap + kk);
        float4 a1 = *(const float4*)(Ap + kk + 4);
        float4 b0 = *(const float4*)(Bp + kk);
        __syncthreads();
        As[alc + 0][alr] = a0.x; As[alc + 1][alr] = a0.y;
        As[alc + 2][alr] = a0.z; As[alc + 3][alr] = a0.w;
        As[alc + 4][alr] = a1.x; As[alc + 5][alr] = a1.y;
        As[alc + 6][alr] = a1.z; As[alc + 7][alr] = a1.w;
        Bs[blc + 0][blr] = b0.x; Bs[blc + 1][blr] = b0.y;
        Bs[blc + 2][blr] = b0.z; Bs[blc + 3][blr] = b0.w;
        __syncthreads();
#pragma unroll
        for (int k = 0; k < 16; k++) {
            const float4 av0 = *(const float4*)&As[k][tr * 8];
            const float4 av1 = *(const float4*)&As[k][tr * 8 + 4];
            const float4 bv  = *(const float4*)&Bs[k][tc * 4];
            float aa[8] = {av0.x, av0.y, av0.z, av0.w, av1.x, av1.y, av1.z, av1.w};
            float bb[4] = {bv.x, bv.y, bv.z, bv.w};
#pragma unroll
            for (int i = 0; i < 8; i++)
#pragma unroll
                for (int j = 0; j < 4; j++)
                    acc[i][j] = fmaf(aa[i], bb[j], acc[i][j]);
        }
    }

#pragma unroll
    for (int i = 0; i < 8; i++) {
        int row = bm * 128 + tr * 8 + i;
#pragma unroll
        for (int j = 0; j < 4; j++) {
            int col = bn * 64 + tc * 4 + j;
            float v = acc[i][j] + bias[col];
            if (XGMODE) v += bias2[col];
            if (SKIP)   v += skip[(size_t)row * Nc + col];
            if (SILU)   v = v * (1.f / (1.f + __expf(-v)));
            if (XGMODE) {
                int q = col >> 10, jj = col & 1023;
                size_t idx = (size_t)row * 16384 + (size_t)lz * 4096
                           + ((size_t)(jj >> 2) << 4) + ((jj & 3) << 2) + q;
                if (XGMODE == 2) Cf[idx] = v;
                else             Cb[idx] = __float2bfloat16(v);
            } else {
                Cf[(size_t)row * Nc + col] = v;
            }
        }
    }
}

// ---------- persistent sequential LSTM chain ----------
// 256 WGs x 256 threads (plain launch; 256 blocks co-resident on 256 CUs).
// WG k owns h/c rows [4k,4k+4). Thread t: d=t>>4 selects (gate q=d&3, row r=d>>2),
// s=t&15 selects the 64-col h slice. Weight row grow = q*1024 + 4k + r, so after
// the 16-lane xor-reduce, wave w (=r) holds all 4 gates of hidden row 4k+w at
// lanes 0/16/32/48 -> gates via intra-wave shuffles, NO second barrier.
// lds_h double-buffered on epoch parity -> single __syncthreads per epoch.
// h broadcast: double-buffered 1024-u64 arrays, word = (fp32 h)<<32 | epoch.
// Deadlock-free: slot for epoch e is only overwritten at e+2, which requires all
// WGs published e+1, which requires all WGs consumed e.
template <typename XT>
__global__ __launch_bounds__(256, 1) void seq_kernel(
    const float* __restrict__ Whh,            // [4][4096][1024]
    const XT* __restrict__ XG,                // [epoch][k*16 + r*4 + q]
    float* __restrict__ hall,                 // [4096][1024]
    uint64_t* hbuf)                           // [2][1024]
{
    const int k = blockIdx.x;
    const int t = threadIdx.x;
    const int d = t >> 4, s = t & 15;
    const int q = d & 3, r = d >> 2;          // r == wave id (t>>6)
    const int ln = t & 63;
    const int grow = q * 1024 + 4 * k + r;
    const int hrow = (k << 2) + r;            // h row this wave publishes

    // rotated weight load: wreg[l][c4*4+j] = Whh[l][grow][s*64 + ((c4+s)&15)*4 + j]
    float wreg[4][64];
#pragma unroll
    for (int l = 0; l < 4; l++) {
        const float* src = Whh + ((size_t)l * H4 + grow) * 1024 + (s << 6);
#pragma unroll
        for (int c4 = 0; c4 < 16; c4++) {
            int ch = (c4 + s) & 15;
            float4 v = *(const float4*)(src + (ch << 2));
            wreg[l][c4 * 4 + 0] = v.x; wreg[l][c4 * 4 + 1] = v.y;
            wreg[l][c4 * 4 + 2] = v.z; wreg[l][c4 * 4 + 3] = v.w;
        }
    }

    __shared__ __align__(16) float lds_h[2][1024];
    float creg = 0.f;   // c for row 4k+r, replicated across the wave

    for (int step = 0; step < NS; ++step) {
#pragma unroll
        for (int l = 0; l < 4; l++) {
            const int it = step * 4 + l + 1;             // epoch being produced
            const uint32_t rtag = (uint32_t)(it - 1);
            uint64_t* rb = (l & 1) ? (hbuf + 1024) : hbuf;        // (it-1)&1 == l&1
            uint64_t* wb = ((l + 1) & 1) ? (hbuf + 1024) : hbuf;  // it&1
            float* lh = lds_h[l & 1];

            // ---- XG prefetch (issued before polling; latency hides behind poll)
            float xg0, xg1, xg2, xg3;
            {
                const XT* p = XG + (size_t)(it - 1) * H4 + (k << 4) + (r << 2);
                if constexpr (sizeof(XT) == 4) {
                    float4 v = *(const float4*)p;
                    xg0 = v.x; xg1 = v.y; xg2 = v.z; xg3 = v.w;
                } else {
                    ushort4 v = *(const ushort4*)p;
                    xg0 = __uint_as_float((uint32_t)v.x << 16);
                    xg1 = __uint_as_float((uint32_t)v.y << 16);
                    xg2 = __uint_as_float((uint32_t)v.z << 16);
                    xg3 = __uint_as_float((uint32_t)v.w << 16);
                }
            }

            // ---- poll + stage h (thread t owns words t, 256+t, 512+t, 768+t)
            uint32_t got = 0;
            int spins = 0;
            while (got != 0xFu) {
#pragma unroll
                for (int m = 0; m < 4; m++) {
                    if (!(got & (1u << m))) {
                        uint64_t u = __hip_atomic_load(&rb[(m << 8) + t],
                                                       __ATOMIC_RELAXED, __HIP_MEMORY_SCOPE_AGENT);
                        if ((uint32_t)u == rtag) {
                            lh[(m << 8) + t] = __uint_as_float((uint32_t)(u >> 32));
                            got |= (1u << m);
                        }
                    }
                }
                if (got != 0xFu && ++spins > 16) __builtin_amdgcn_s_sleep(1);
            }
            __syncthreads();   // B1: lds_h complete (only barrier per epoch)

            // ---- partial dot over this thread's 64-col slice (rotated reads)
            float acc = 0.f;
            const float* hbase = lh + (s << 6);
#pragma unroll
            for (int c4 = 0; c4 < 16; c4++) {
                int ch = (c4 + s) & 15;
                const float4 hv = *(const float4*)(hbase + (ch << 2));
                acc = fmaf(wreg[l][c4 * 4 + 0], hv.x, acc);
                acc = fmaf(wreg[l][c4 * 4 + 1], hv.y, acc);
                acc = fmaf(wreg[l][c4 * 4 + 2], hv.z, acc);
                acc = fmaf(wreg[l][c4 * 4 + 3], hv.w, acc);
            }
            // reduce the 16 sub-slices (xor 1,2,4,8 stays within each 16-lane group)
            acc += __shfl_xor(acc, 1);
            acc += __shfl_xor(acc, 2);
            acc += __shfl_xor(acc, 4);
            acc += __shfl_xor(acc, 8);

            // gate value for this lane's group: add XG component (q4 = ln>>4)
            int q4 = ln >> 4;
            float xa = (q4 & 2) ? ((q4 & 1) ? xg3 : xg2) : ((q4 & 1) ? xg1 : xg0);
            float gval = acc + xa;

            // wave w holds gates i,f,g,o of row 4k+w at lanes 0,16,32,48
            float gi = __shfl(gval, 0);
            float gf = __shfl(gval, 16);
            float gG = __shfl(gval, 32);
            float go = __shfl(gval, 48);
            float cn = sigm_f(gf) * creg + sigm_f(gi) * tanh_f(gG);
            creg = cn;
            float hn = sigm_f(go) * tanh_f(cn);

            if (ln == 0) {
                if (l == 3) hall[(size_t)step * 1024 + hrow] = hn;
                uint64_t word = ((uint64_t)__float_as_uint(hn) << 32) | (uint64_t)(uint32_t)it;
                __hip_atomic_store(&wb[hrow], word,
                                   __ATOMIC_RELAXED, __HIP_MEMORY_SCOPE_AGENT);
            }
        }
    }
}

extern "C" void kernel_launch(void* const* d_in, const int* in_sizes, int n_in,
                              void* d_out, int out_size, void* d_ws, size_t ws_size,
                              hipStream_t stream)
{
    const float* x      = (const float*)d_in[0];
    const int*   ts     = (const int*)d_in[1];
    const float* proj_w = (const float*)d_in[2];
    const float* proj_b = (const float*)d_in[3];
    const float* te_w1  = (const float*)d_in[4];
    const float* te_b1  = (const float*)d_in[5];
    const float* te_w2  = (const float*)d_in[6];
    const float* te_b2  = (const float*)d_in[7];
    const float* Wih    = (const float*)d_in[8];
    const float* Whh    = (const float*)d_in[9];
    const float* bih    = (const float*)d_in[10];
    const float* bhh    = (const float*)d_in[11];
    const float* lin_w  = (const float*)d_in[12];
    const float* lin_b  = (const float*)d_in[13];
    float* out = (float*)d_out;

    char* ws = (char*)d_ws;
    const size_t MB16 = (size_t)NS * DT * 4;                    // 16 MiB
    float* bufA = (float*)ws;                                   // emb -> emb2 -> hall
    float* bufB = (float*)(ws + MB16);                          // h1 -> xp
    const size_t xg_f32_bytes  = (size_t)NS * 16384 * 4;        // 256 MiB
    const size_t xg_bf16_bytes = (size_t)NS * 16384 * 2;        // 128 MiB
    const bool use_f32_xg = ws_size >= 2 * MB16 + xg_f32_bytes + 16384 + 64;
    float*          XGf = (float*)(ws + 2 * MB16);
    __hip_bfloat16* XGb = (__hip_bfloat16*)(ws + 2 * MB16);
    uint64_t* hbuf = (uint64_t*)(ws + 2 * MB16 +
                                 (use_f32_xg ? xg_f32_bytes : xg_bf16_bytes));

    hipMemsetAsync(hbuf, 0, 2 * 1024 * sizeof(uint64_t), stream);

    // emb = sinusoidal(timesteps)
    emb_kernel<<<NS, 512, 0, stream>>>(ts, bufA);
    // h1 = silu(emb @ te_w1^T + te_b1)
    gemm_bt<true, false, 0><<<dim3(16, 32), 256, 0, stream>>>(
        bufA, te_w1, te_b1, nullptr, nullptr, bufB, nullptr, NS, DT, DT);
    // emb2 = h1 @ te_w2^T + te_b2
    gemm_bt<false, false, 0><<<dim3(16, 32), 256, 0, stream>>>(
        bufB, te_w2, te_b2, nullptr, nullptr, bufA, nullptr, NS, DT, DT);
    // xp = x @ proj_w^T + proj_b + emb2
    gemm_bt<false, true, 0><<<dim3(16, 32), 256, 0, stream>>>(
        x, proj_w, proj_b, nullptr, bufA, bufB, nullptr, NS, DT, DT);
    // XG[l] = xp @ Wih[l]^T + bih[l] + bhh[l]   (permuted layout), z = layer
    if (use_f32_xg) {
        gemm_bt<false, false, 2><<<dim3(64, 32, 4), 256, 0, stream>>>(
            bufB, Wih, bih, bhh, nullptr, XGf, nullptr, NS, H4, DT);
        seq_kernel<float><<<256, 256, 0, stream>>>(Whh, XGf, bufA, hbuf);
    } else {
        gemm_bt<false, false, 1><<<dim3(64, 32, 4), 256, 0, stream>>>(
            bufB, Wih, bih, bhh, nullptr, nullptr, XGb, NS, H4, DT);
        seq_kernel<__hip_bfloat16><<<256, 256, 0, stream>>>(Whh, XGb, bufA, hbuf);
    }
    // out = hall @ lin_w^T + lin_b
    gemm_bt<false, false, 0><<<dim3(16, 32), 256, 0, stream>>>(
        bufA, lin_w, lin_b, nullptr, nullptr, out, nullptr, NS, DT, DT);
}

// Round 4
// 42341.501 us; speedup vs baseline: 1.4753x; 1.4753x over previous
//
#include <hip/hip_runtime.h>
#include <hip/hip_bf16.h>
#include <stdint.h>

#define NS 4096     // samples / time steps
#define DT 1024     // dim_t == hidden == in
#define H4 4096     // 4*HID

// ---------- math helpers ----------
__device__ __forceinline__ float sigm_f(float x) { return 1.f / (1.f + __expf(-x)); }
__device__ __forceinline__ float tanh_f(float x) {
    float ax = fminf(fabsf(x), 15.f);                 // overflow-safe
    float t = 1.f - 2.f / (__expf(2.f * ax) + 1.f);
    return copysignf(t, x);
}

// ---------- sinusoidal embedding ----------
__global__ void emb_kernel(const int* __restrict__ ts, float* __restrict__ emb) {
    int t = blockIdx.x;
    int i = threadIdx.x;                 // 0..511
    float tv = (float)ts[t];
    const float c = -0.018024149455922082f;  // -ln(10000)/511
    float f = __expf(c * (float)i);
    float a = tv * f;
    float s, co;
    sincosf(a, &s, &co);
    emb[(size_t)t * DT + i] = s;
    emb[(size_t)t * DT + 512 + i] = co;
}

// ---------- generic C = A(M,K) @ B(Nc,K)^T + bias [+bias2] [+skip] [silu] ----------
// BM=128, BN=64, BK=16, 256 threads, each thread 8x4 outputs.
// XGMODE: 0 = plain fp32 C; 1 = bf16 XG layout; 2 = fp32 XG layout.
// XG layout per epoch (4096 elems): pos = k*16 + r*4 + q for col = q*1024 + 4k + r.
template <bool SILU, bool SKIP, int XGMODE>
__global__ __launch_bounds__(256) void gemm_bt(
    const float* __restrict__ A, const float* __restrict__ B,
    const float* __restrict__ bias, const float* __restrict__ bias2,
    const float* __restrict__ skip, float* __restrict__ Cf,
    __hip_bfloat16* __restrict__ Cb, int M, int Nc, int K)
{
    __shared__ __align__(16) float As[16][132];
    __shared__ __align__(16) float Bs[16][68];
    const int bn = blockIdx.x, bm = blockIdx.y, lz = blockIdx.z;
    if (XGMODE) {
        B     += (size_t)lz * H4 * DT;
        bias  += (size_t)lz * H4;
        bias2 += (size_t)lz * H4;
    }
    const int tid = threadIdx.x;
    const int tr = tid >> 4, tc = tid & 15;
    const int alr = tid >> 1, alc = (tid & 1) << 3;   // A: 128 rows x 16 cols
    const int blr = tid >> 2, blc = (tid & 3) << 2;   // B: 64 rows x 16 cols
    const float* Ap = A + (size_t)(bm * 128 + alr) * K + alc;
    const float* Bp = B + (size_t)(bn * 64 + blr) * K + blc;

    float acc[8][4];
#pragma unroll
    for (int i = 0; i < 8; i++)
#pragma unroll
        for (int j = 0; j < 4; j++) acc[i][j] = 0.f;

    for (int kk = 0; kk < K; kk += 16) {
        float4 a0 = *(const float4*)(Ap + kk);
        float4 a1 = *(const float4*)(Ap + kk + 4);
        float4 b0 = *(const float4*)(Bp + kk);
        __syncthreads();
        As[alc + 0][alr] = a0.x; As[alc + 1][alr] = a0.y;
        As[alc + 2][alr] = a0.z; As[alc + 3][alr] = a0.w;
        As[alc + 4][alr] = a1.x; As[alc + 5][alr] = a1.y;
        As[alc + 6][alr] = a1.z; As[alc + 7][alr] = a1.w;
        Bs[blc + 0][blr] = b0.x; Bs[blc + 1][blr] = b0.y;
        Bs[blc + 2][blr] = b0.z; Bs[blc + 3][blr] = b0.w;
        __syncthreads();
#pragma unroll
        for (int k = 0; k < 16; k++) {
            const float4 av0 = *(const float4*)&As[k][tr * 8];
            const float4 av1 = *(const float4*)&As[k][tr * 8 + 4];
            const float4 bv  = *(const float4*)&Bs[k][tc * 4];
            float aa[8] = {av0.x, av0.y, av0.z, av0.w, av1.x, av1.y, av1.z, av1.w};
            float bb[4] = {bv.x, bv.y, bv.z, bv.w};
#pragma unroll
            for (int i = 0; i < 8; i++)
#pragma unroll
                for (int j = 0; j < 4; j++)
                    acc[i][j] = fmaf(aa[i], bb[j], acc[i][j]);
        }
    }

#pragma unroll
    for (int i = 0; i < 8; i++) {
        int row = bm * 128 + tr * 8 + i;
#pragma unroll
        for (int j = 0; j < 4; j++) {
            int col = bn * 64 + tc * 4 + j;
            float v = acc[i][j] + bias[col];
            if (XGMODE) v += bias2[col];
            if (SKIP)   v += skip[(size_t)row * Nc + col];
            if (SILU)   v = v * (1.f / (1.f + __expf(-v)));
            if (XGMODE) {
                int q = col >> 10, jj = col & 1023;
                size_t idx = (size_t)row * 16384 + (size_t)lz * 4096
                           + ((size_t)(jj >> 2) << 4) + ((jj & 3) << 2) + q;
                if (XGMODE == 2) Cf[idx] = v;
                else             Cb[idx] = __float2bfloat16(v);
            } else {
                Cf[(size_t)row * Nc + col] = v;
            }
        }
    }
}

// ---------- persistent sequential LSTM chain ----------
// 256 WGs x 256 threads (plain launch; 256 blocks co-resident on 256 CUs).
// WG k owns h/c rows [4k,4k+4).
// Dot mapping (broadcast-optimized): lane = (j = t&15, cg = (t>>4)&3), wave w.
// Lane computes g-row d=j (r=j>>2, q=j&3, grow=q*1024+4k+r) over cols
// 256w + 64cg + [0,64). The 16 lanes sharing cg read the SAME LDS address
// -> free broadcast; LDS dot traffic drops 16x vs per-lane slices.
// Rotation (i+4cg)&15 keeps residual conflicts 2-way (free).
// Cross-wave reduce via 64-float lds_p + B2; gates+publish by threads t<4 of
// wave 0 -> 4 consecutive u64 stores = one coalesced 32B fabric write.
// h broadcast: double-buffered 1024-u64 arrays, word = (fp32 h)<<32 | epoch.
// Deadlock-free: slot for epoch e is only overwritten at e+2, which requires
// all WGs published e+1, which requires all WGs consumed e.
template <typename XT>
__global__ __launch_bounds__(256, 1) void seq_kernel(
    const float* __restrict__ Whh,            // [4][4096][1024]
    const XT* __restrict__ XG,                // [epoch][k*16 + r*4 + q]
    float* __restrict__ hall,                 // [4096][1024]
    uint64_t* hbuf)                           // [2][1024]
{
    const int k = blockIdx.x;
    const int t = threadIdx.x;
    const int j = t & 15;                     // g-row index d
    const int cg = (t >> 4) & 3;              // 64-col sub-chunk
    const int w = t >> 6;                     // wave id
    const int q = j & 3, r = j >> 2;
    const int grow = q * 1024 + 4 * k + r;

    // weights, rotated to match the rotated LDS reads:
    // wreg[l][i*4+e] = Whh[l][grow][256w + 64cg + 4*((i+4cg)&15) + e]
    float wreg[4][64];
#pragma unroll
    for (int l = 0; l < 4; l++) {
        const float* src = Whh + ((size_t)l * H4 + grow) * 1024 + (w << 8) + (cg << 6);
#pragma unroll
        for (int i = 0; i < 16; i++) {
            int ii = (i + 4 * cg) & 15;
            float4 v = *(const float4*)(src + (ii << 2));
            wreg[l][i * 4 + 0] = v.x; wreg[l][i * 4 + 1] = v.y;
            wreg[l][i * 4 + 2] = v.z; wreg[l][i * 4 + 3] = v.w;
        }
    }

    __shared__ __align__(16) float lh[1024];
    __shared__ __align__(16) float lds_p[64];
    float creg = 0.f;   // c for row 4k+t (threads t<4 only)

    for (int step = 0; step < NS; ++step) {
#pragma unroll
        for (int l = 0; l < 4; l++) {
            const int it = step * 4 + l + 1;             // epoch being produced
            const uint32_t rtag = (uint32_t)(it - 1);
            uint64_t* rb = (l & 1) ? (hbuf + 1024) : hbuf;        // (it-1)&1 == l&1
            uint64_t* wb = ((l + 1) & 1) ? (hbuf + 1024) : hbuf;  // it&1

            // ---- XG prefetch by gate threads, issued BEFORE polling
            float xg0 = 0.f, xg1 = 0.f, xg2 = 0.f, xg3 = 0.f;
            if (t < 4) {
                const XT* p = XG + (size_t)(it - 1) * H4 + (k << 4) + (t << 2);
                if constexpr (sizeof(XT) == 4) {
                    float4 v = *(const float4*)p;
                    xg0 = v.x; xg1 = v.y; xg2 = v.z; xg3 = v.w;
                } else {
                    ushort4 v = *(const ushort4*)p;
                    xg0 = __uint_as_float((uint32_t)v.x << 16);
                    xg1 = __uint_as_float((uint32_t)v.y << 16);
                    xg2 = __uint_as_float((uint32_t)v.z << 16);
                    xg3 = __uint_as_float((uint32_t)v.w << 16);
                }
            }

            // ---- poll + stage h (thread t owns words t, 256+t, 512+t, 768+t)
            uint32_t got = 0;
            while (got != 0xFu) {
#pragma unroll
                for (int m = 0; m < 4; m++) {
                    if (!(got & (1u << m))) {
                        uint64_t u = __hip_atomic_load(&rb[(m << 8) + t],
                                                       __ATOMIC_RELAXED, __HIP_MEMORY_SCOPE_AGENT);
                        if ((uint32_t)u == rtag) {
                            lh[(m << 8) + t] = __uint_as_float((uint32_t)(u >> 32));
                            got |= (1u << m);
                        }
                    }
                }
            }
            __syncthreads();   // B1: lh complete

            // ---- broadcast dot: 16 lanes/address, rotated, 4 accumulators
            const float* hbase = lh + (w << 8) + (cg << 6);
            float a0 = 0.f, a1 = 0.f, a2 = 0.f, a3 = 0.f;
#pragma unroll
            for (int i = 0; i < 16; i++) {
                int ii = (i + 4 * cg) & 15;
                const float4 hv = *(const float4*)(hbase + (ii << 2));
                a0 = fmaf(wreg[l][i * 4 + 0], hv.x, a0);
                a1 = fmaf(wreg[l][i * 4 + 1], hv.y, a1);
                a2 = fmaf(wreg[l][i * 4 + 2], hv.z, a2);
                a3 = fmaf(wreg[l][i * 4 + 3], hv.w, a3);
            }
            float acc = (a0 + a1) + (a2 + a3);
            // reduce the 4 cg-chunks (lanes j, j+16, j+32, j+48)
            acc += __shfl_xor(acc, 16);
            acc += __shfl_xor(acc, 32);
            if ((t & 63) < 16) lds_p[(j << 2) + w] = acc;   // [j][w]
            __syncthreads();   // B2: lds_p complete

            if (t < 4) {
                // g[q] for hidden row 4k+t: sum lds_p[(t*4+q)*4 + w] over w
                const float4 p0 = *(const float4*)&lds_p[(t << 4) + 0];
                const float4 p1 = *(const float4*)&lds_p[(t << 4) + 4];
                const float4 p2 = *(const float4*)&lds_p[(t << 4) + 8];
                const float4 p3 = *(const float4*)&lds_p[(t << 4) + 12];
                float gi = (p0.x + p0.y) + (p0.z + p0.w) + xg0;
                float gf = (p1.x + p1.y) + (p1.z + p1.w) + xg1;
                float gG = (p2.x + p2.y) + (p2.z + p2.w) + xg2;
                float go = (p3.x + p3.y) + (p3.z + p3.w) + xg3;
                float cn = sigm_f(gf) * creg + sigm_f(gi) * tanh_f(gG);
                creg = cn;
                float hn = sigm_f(go) * tanh_f(cn);
                if (l == 3) hall[(size_t)step * 1024 + (k << 2) + t] = hn;
                uint64_t word = ((uint64_t)__float_as_uint(hn) << 32) | (uint64_t)(uint32_t)it;
                __hip_atomic_store(&wb[(k << 2) + t], word,
                                   __ATOMIC_RELAXED, __HIP_MEMORY_SCOPE_AGENT);
            }
        }
    }
}

extern "C" void kernel_launch(void* const* d_in, const int* in_sizes, int n_in,
                              void* d_out, int out_size, void* d_ws, size_t ws_size,
                              hipStream_t stream)
{
    const float* x      = (const float*)d_in[0];
    const int*   ts     = (const int*)d_in[1];
    const float* proj_w = (const float*)d_in[2];
    const float* proj_b = (const float*)d_in[3];
    const float* te_w1  = (const float*)d_in[4];
    const float* te_b1  = (const float*)d_in[5];
    const float* te_w2  = (const float*)d_in[6];
    const float* te_b2  = (const float*)d_in[7];
    const float* Wih    = (const float*)d_in[8];
    const float* Whh    = (const float*)d_in[9];
    const float* bih    = (const float*)d_in[10];
    const float* bhh    = (const float*)d_in[11];
    const float* lin_w  = (const float*)d_in[12];
    const float* lin_b  = (const float*)d_in[13];
    float* out = (float*)d_out;

    char* ws = (char*)d_ws;
    const size_t MB16 = (size_t)NS * DT * 4;                    // 16 MiB
    float* bufA = (float*)ws;                                   // emb -> emb2 -> hall
    float* bufB = (float*)(ws + MB16);                          // h1 -> xp
    const size_t xg_f32_bytes  = (size_t)NS * 16384 * 4;        // 256 MiB
    const size_t xg_bf16_bytes = (size_t)NS * 16384 * 2;        // 128 MiB
    const bool use_f32_xg = ws_size >= 2 * MB16 + xg_f32_bytes + 16384 + 64;
    float*          XGf = (float*)(ws + 2 * MB16);
    __hip_bfloat16* XGb = (__hip_bfloat16*)(ws + 2 * MB16);
    uint64_t* hbuf = (uint64_t*)(ws + 2 * MB16 +
                                 (use_f32_xg ? xg_f32_bytes : xg_bf16_bytes));

    hipMemsetAsync(hbuf, 0, 2 * 1024 * sizeof(uint64_t), stream);

    // emb = sinusoidal(timesteps)
    emb_kernel<<<NS, 512, 0, stream>>>(ts, bufA);
    // h1 = silu(emb @ te_w1^T + te_b1)
    gemm_bt<true, false, 0><<<dim3(16, 32), 256, 0, stream>>>(
        bufA, te_w1, te_b1, nullptr, nullptr, bufB, nullptr, NS, DT, DT);
    // emb2 = h1 @ te_w2^T + te_b2
    gemm_bt<false, false, 0><<<dim3(16, 32), 256, 0, stream>>>(
        bufB, te_w2, te_b2, nullptr, nullptr, bufA, nullptr, NS, DT, DT);
    // xp = x @ proj_w^T + proj_b + emb2
    gemm_bt<false, true, 0><<<dim3(16, 32), 256, 0, stream>>>(
        x, proj_w, proj_b, nullptr, bufA, bufB, nullptr, NS, DT, DT);
    // XG[l] = xp @ Wih[l]^T + bih[l] + bhh[l]   (permuted layout), z = layer
    if (use_f32_xg) {
        gemm_bt<false, false, 2><<<dim3(64, 32, 4), 256, 0, stream>>>(
            bufB, Wih, bih, bhh, nullptr, XGf, nullptr, NS, H4, DT);
        seq_kernel<float><<<256, 256, 0, stream>>>(Whh, XGf, bufA, hbuf);
    } else {
        gemm_bt<false, false, 1><<<dim3(64, 32, 4), 256, 0, stream>>>(
            bufB, Wih, bih, bhh, nullptr, nullptr, XGb, NS, H4, DT);
        seq_kernel<__hip_bfloat16><<<256, 256, 0, stream>>>(Whh, XGb, bufA, hbuf);
    }
    // out = hall @ lin_w^T + lin_b
    gemm_bt<false, false, 0><<<dim3(16, 32), 256, 0, stream>>>(
        bufA, lin_w, lin_b, nullptr, nullptr, out, nullptr, NS, DT, DT);
}